// Round 3
// baseline (780.230 us; speedup 1.0000x reference)
//
#include <hip/hip_runtime.h>
#include <math.h>

#define DDIM 1024
#define BQ 256
#define EPSV 1e-8f
#define CH 8
#define TPC 16
#define NCAND (CH * TPC)

typedef short bf16x8 __attribute__((ext_vector_type(8)));
typedef float f32x4 __attribute__((ext_vector_type(4)));

__device__ __forceinline__ unsigned short f2bf(float x) {
  union { float f; unsigned int u; } v;
  v.f = x;
  unsigned int lsb = (v.u >> 16) & 1u;
  v.u += 0x7fffu + lsb;  // round-to-nearest-even
  return (unsigned short)(v.u >> 16);
}
__device__ __forceinline__ float bf2f(unsigned short b) {
  union { unsigned int u; float f; } v;
  v.u = ((unsigned int)b) << 16;
  return v.f;
}

#define ASYNC_CP16(gp, lp)                                                     \
  __builtin_amdgcn_global_load_lds(                                            \
      (const __attribute__((address_space(1))) unsigned int*)(const void*)(gp),\
      (__attribute__((address_space(3))) unsigned int*)(lp), 16, 0, 0)

// ---------------- prep: Q fp32 -> bf16, qn ----------------
__global__ __launch_bounds__(256) void prep_q(const float* __restrict__ Q,
                                              unsigned short* __restrict__ Qb,
                                              float* __restrict__ qn) {
  int wave = threadIdx.x >> 6, lane = threadIdx.x & 63;
  int q = blockIdx.x * 4 + wave;
  const float4* src = (const float4*)(Q + (size_t)q * DDIM);
  unsigned short* dst = Qb + (size_t)q * DDIM;
  float s = 0.f;
#pragma unroll
  for (int t = 0; t < 4; ++t) {
    float4 v = src[t * 64 + lane];
    s += v.x * v.x + v.y * v.y + v.z * v.z + v.w * v.w;
    ushort4 o;
    o.x = f2bf(v.x); o.y = f2bf(v.y); o.z = f2bf(v.z); o.w = f2bf(v.w);
    *(ushort4*)(dst + t * 256 + lane * 4) = o;
  }
#pragma unroll
  for (int o = 32; o > 0; o >>= 1) s += __shfl_down(s, o, 64);
  if (lane == 0) qn[q] = sqrtf(s);
}

// ---------------- MFMA GEMM: 256 q x 64 n per block, sims = bf16(dot/||m||) --
__global__ __launch_bounds__(256) void gemm_topk(
    const float* __restrict__ M, const unsigned short* __restrict__ Qb,
    unsigned short* __restrict__ sims, int N, int Npitch) {
  __shared__ unsigned short Qs[256 * 32];  // [q][k], 64 B rows
  __shared__ unsigned short Ms[64 * 32];   // [n][k]
  __shared__ float Rs[64];                 // 1/||m|| per block row
  const int tid = threadIdx.x;
  const int wave = tid >> 6, lane = tid & 63;
  const int quad = lane >> 4, l15 = lane & 15;
  const int n0 = blockIdx.x * 64;

  const int mrow = tid >> 2;    // 0..63
  const int mchunk = tid & 3;   // 0..3, 8 floats each
  const bool mvalid = (n0 + mrow) < N;
  const float* mptr = M + (size_t)(mvalid ? (n0 + mrow) : 0) * DDIM + mchunk * 8;

  f32x4 acc[4][4];
#pragma unroll
  for (int i = 0; i < 4; ++i)
#pragma unroll
    for (int j = 0; j < 4; ++j) acc[i][j] = (f32x4){0.f, 0.f, 0.f, 0.f};
  float sumsq = 0.f;

  // preload k0 = 0
  float4 m0 = make_float4(0.f, 0.f, 0.f, 0.f), m1 = m0;
  if (mvalid) {
    m0 = *(const float4*)(mptr);
    m1 = *(const float4*)(mptr + 4);
  }

  for (int k0 = 0; k0 < DDIM; k0 += 32) {
    __syncthreads();  // previous iteration's LDS reads done
    // Q tile async global->LDS (Qb already bf16). 4 rounds x 4 waves x 16 rows.
#pragma unroll
    for (int r = 0; r < 4; ++r) {
      int row0 = r * 64 + wave * 16;  // wave-uniform
      const unsigned short* g =
          Qb + (size_t)(row0 + (lane >> 2)) * DDIM + k0 + (lane & 3) * 8;
      ASYNC_CP16(g, &Qs[row0 * 32]);
    }
    // M tile from prefetched regs: sumsq + convert + LDS write (16 B)
    sumsq += m0.x * m0.x + m0.y * m0.y + m0.z * m0.z + m0.w * m0.w +
             m1.x * m1.x + m1.y * m1.y + m1.z * m1.z + m1.w * m1.w;
    uint4 packed;
    packed.x = (unsigned int)f2bf(m0.x) | ((unsigned int)f2bf(m0.y) << 16);
    packed.y = (unsigned int)f2bf(m0.z) | ((unsigned int)f2bf(m0.w) << 16);
    packed.z = (unsigned int)f2bf(m1.x) | ((unsigned int)f2bf(m1.y) << 16);
    packed.w = (unsigned int)f2bf(m1.z) | ((unsigned int)f2bf(m1.w) << 16);
    *(uint4*)&Ms[mrow * 32 + mchunk * 8] = packed;
    __syncthreads();
    // register-prefetch next M chunk: full MFMA window + next barrier of slack
    float4 m0n = make_float4(0.f, 0.f, 0.f, 0.f), m1n = m0n;
    if (k0 + 32 < DDIM && mvalid) {
      m0n = *(const float4*)(mptr + k0 + 32);
      m1n = *(const float4*)(mptr + k0 + 36);
    }
    // MFMA: wave handles q in [wave*64, wave*64+64), n in [0,64)
    bf16x8 afr[4], bfr[4];
#pragma unroll
    for (int i = 0; i < 4; ++i)
      afr[i] = *(const bf16x8*)&Qs[(wave * 64 + i * 16 + l15) * 32 + quad * 8];
#pragma unroll
    for (int j = 0; j < 4; ++j)
      bfr[j] = *(const bf16x8*)&Ms[(j * 16 + l15) * 32 + quad * 8];
#pragma unroll
    for (int i = 0; i < 4; ++i)
#pragma unroll
      for (int j = 0; j < 4; ++j)
        acc[i][j] = __builtin_amdgcn_mfma_f32_16x16x32_bf16(afr[i], bfr[j],
                                                            acc[i][j], 0, 0, 0);
    m0 = m0n;
    m1 = m1n;
  }

  // 1/||m|| for this block's 64 rows (exact fp32 sums from staging data)
  float s = sumsq;
  s += __shfl_xor(s, 1, 64);
  s += __shfl_xor(s, 2, 64);
  if (mchunk == 0) Rs[mrow] = (s > 0.f) ? rsqrtf(s) : 0.f;
  __syncthreads();
  float rj[4];
#pragma unroll
  for (int j = 0; j < 4; ++j) rj[j] = Rs[j * 16 + l15];

  // store bf16 (dot / ||m||)
#pragma unroll
  for (int i = 0; i < 4; ++i)
#pragma unroll
    for (int j = 0; j < 4; ++j)
#pragma unroll
      for (int r = 0; r < 4; ++r) {
        int q = wave * 64 + i * 16 + quad * 4 + r;
        int n = n0 + j * 16 + l15;
        sims[(size_t)q * Npitch + n] = f2bf(acc[i][j][r] * rj[j]);
      }
}

// ---------------- helpers ----------------
__device__ __forceinline__ bool better(float v1, int i1, float v2, int i2) {
  return v1 > v2 || (v1 == v2 && i1 < i2);
}

template <int L>
__device__ __forceinline__ void insert_topL(float (&tv)[L], int (&ti)[L],
                                            float v, int idx) {
  if (v > tv[L - 1] || (v == tv[L - 1] && idx < ti[L - 1])) {
    tv[L - 1] = v; ti[L - 1] = idx;
#pragma unroll
    for (int j = L - 1; j > 0; --j) {
      if (better(tv[j], ti[j], tv[j - 1], ti[j - 1])) {
        float fv = tv[j]; tv[j] = tv[j - 1]; tv[j - 1] = fv;
        int ii = ti[j]; ti[j] = ti[j - 1]; ti[j - 1] = ii;
      }
    }
  }
}

// block tournament over per-thread sorted lists (NW waves per block).
template <int L, int NW, typename F>
__device__ __forceinline__ void block_extract(float (&tv)[L], int (&ti)[L],
                                              int rounds, F&& emit) {
  __shared__ float s_v[NW];
  __shared__ int s_i[NW];
  __shared__ int s_t[NW];
  __shared__ float s_wv;
  __shared__ int s_wi;
  __shared__ int s_wt;
  for (int r = 0; r < rounds; ++r) {
    float v = tv[0];
    int idx = ti[0];
    int src = threadIdx.x;
#pragma unroll
    for (int o = 32; o > 0; o >>= 1) {
      float ov = __shfl_down(v, o, 64);
      int oi = __shfl_down(idx, o, 64);
      int os = __shfl_down(src, o, 64);
      if (better(ov, oi, v, idx)) { v = ov; idx = oi; src = os; }
    }
    int lane = threadIdx.x & 63, w = threadIdx.x >> 6;
    if (lane == 0) { s_v[w] = v; s_i[w] = idx; s_t[w] = src; }
    __syncthreads();
    if (threadIdx.x == 0) {
      float bv = s_v[0]; int bi = s_i[0]; int bt = s_t[0];
      for (int w2 = 1; w2 < NW; ++w2)
        if (better(s_v[w2], s_i[w2], bv, bi)) { bv = s_v[w2]; bi = s_i[w2]; bt = s_t[w2]; }
      s_wv = bv; s_wi = bi; s_wt = bt;
    }
    __syncthreads();
    if (threadIdx.x == s_wt) {
#pragma unroll
      for (int j = 0; j < L - 1; ++j) { tv[j] = tv[j + 1]; ti[j] = ti[j + 1]; }
      tv[L - 1] = -INFINITY; ti[L - 1] = 0x7fffffff;
    }
    if (threadIdx.x == 0) emit(r, s_wv, s_wi);
    __syncthreads();
  }
}

// ---------------- selection: per (q, chunk) top-16 by bf16 cos ----------------
__global__ __launch_bounds__(512) void select_chunks(
    const unsigned short* __restrict__ sims, int* __restrict__ cand,
    int N, int Npitch, int Nc) {
  int q = blockIdx.y;
  int c = blockIdx.x;
  int start = c * Nc;
  int end = start + Nc;
  if (end > N) end = N;
  float tv[16]; int ti[16];
#pragma unroll
  for (int j = 0; j < 16; ++j) { tv[j] = -INFINITY; ti[j] = 0x7fffffff; }
  const unsigned short* row = sims + (size_t)q * Npitch;
  int base = start + threadIdx.x * 8;
  for (; base + 8 <= end; base += 4096) {
    uint4 wv = *(const uint4*)(row + base);
    float f0 = bf2f((unsigned short)(wv.x & 0xffff));
    float f1 = bf2f((unsigned short)(wv.x >> 16));
    float f2 = bf2f((unsigned short)(wv.y & 0xffff));
    float f3 = bf2f((unsigned short)(wv.y >> 16));
    float f4 = bf2f((unsigned short)(wv.z & 0xffff));
    float f5 = bf2f((unsigned short)(wv.z >> 16));
    float f6 = bf2f((unsigned short)(wv.w & 0xffff));
    float f7 = bf2f((unsigned short)(wv.w >> 16));
    insert_topL<16>(tv, ti, f0, base + 0);
    insert_topL<16>(tv, ti, f1, base + 1);
    insert_topL<16>(tv, ti, f2, base + 2);
    insert_topL<16>(tv, ti, f3, base + 3);
    insert_topL<16>(tv, ti, f4, base + 4);
    insert_topL<16>(tv, ti, f5, base + 5);
    insert_topL<16>(tv, ti, f6, base + 6);
    insert_topL<16>(tv, ti, f7, base + 7);
  }
  // ragged tail
  if (base < end) {
    int stop = end - base < 8 ? end : base + 8;
    for (int n = base; n < stop; ++n)
      insert_topL<16>(tv, ti, bf2f(row[n]), n);
  }
  int* dst = cand + (size_t)q * NCAND + c * TPC;
  block_extract<16, 8>(tv, ti, TPC, [&](int r, float v, int i) {
    dst[r] = (i == 0x7fffffff) ? 0 : i;
  });
}

// ---------------- rescore candidates in fp32, final top-16 ----------------
__global__ __launch_bounds__(512) void rescore(
    const float* __restrict__ Q, const float* __restrict__ M,
    const float* __restrict__ qn, const int* __restrict__ cand,
    float* __restrict__ out, int N) {
  __shared__ float cosv[NCAND];
  __shared__ int cidx[NCAND];
  int q = blockIdx.x;
  int wave = threadIdx.x >> 6, lane = threadIdx.x & 63;
  const float4* qf4 = (const float4*)(Q + (size_t)q * DDIM);
  float4 qv[4];
#pragma unroll
  for (int t = 0; t < 4; ++t) qv[t] = qf4[t * 64 + lane];
  float qnv = qn[q];
  const int per = NCAND / 8;  // 16 candidates per wave, 2 in flight
#pragma unroll 1
  for (int i = 0; i < per; i += 2) {
    int cA = wave * per + i;
    int cB = cA + 1;
    int idxA = cand[(size_t)q * NCAND + cA];
    int idxB = cand[(size_t)q * NCAND + cB];
    if (idxA < 0 || idxA >= N) idxA = 0;
    if (idxB < 0 || idxB >= N) idxB = 0;
    const float4* mA = (const float4*)(M + (size_t)idxA * DDIM);
    const float4* mB = (const float4*)(M + (size_t)idxB * DDIM);
    float dA = 0.f, sA = 0.f, dB = 0.f, sB = 0.f;
#pragma unroll
    for (int t = 0; t < 4; ++t) {
      float4 a = mA[t * 64 + lane];
      float4 b = mB[t * 64 + lane];
      dA += a.x * qv[t].x + a.y * qv[t].y + a.z * qv[t].z + a.w * qv[t].w;
      sA += a.x * a.x + a.y * a.y + a.z * a.z + a.w * a.w;
      dB += b.x * qv[t].x + b.y * qv[t].y + b.z * qv[t].z + b.w * qv[t].w;
      sB += b.x * b.x + b.y * b.y + b.z * b.z + b.w * b.w;
    }
#pragma unroll
    for (int o = 32; o > 0; o >>= 1) {
      dA += __shfl_down(dA, o, 64);
      sA += __shfl_down(sA, o, 64);
      dB += __shfl_down(dB, o, 64);
      sB += __shfl_down(sB, o, 64);
    }
    if (lane == 0) {
      cosv[cA] = dA / fmaxf(qnv * sqrtf(sA), EPSV);
      cidx[cA] = idxA;
      cosv[cB] = dB / fmaxf(qnv * sqrtf(sB), EPSV);
      cidx[cB] = idxB;
    }
  }
  __syncthreads();
  if (wave == 0) {
    float v0 = cosv[lane], v1 = cosv[lane + 64];
    int i0 = cidx[lane], i1 = cidx[lane + 64];
    for (int r = 0; r < 16; ++r) {
      bool fb = better(v0, i0, v1, i1);
      float bv = fb ? v0 : v1;
      int bi = fb ? i0 : i1;
      int bs = lane * 2 + (fb ? 0 : 1);
#pragma unroll
      for (int o = 32; o > 0; o >>= 1) {
        float ov = __shfl_down(bv, o, 64);
        int oi = __shfl_down(bi, o, 64);
        int os = __shfl_down(bs, o, 64);
        if (better(ov, oi, bv, bi)) { bv = ov; bi = oi; bs = os; }
      }
      bv = __shfl(bv, 0, 64);
      bi = __shfl(bi, 0, 64);
      bs = __shfl(bs, 0, 64);
      if (lane == (bs >> 1)) {
        if (bs & 1) v1 = -INFINITY; else v0 = -INFINITY;
      }
      if (lane == 0) {
        out[(size_t)q * 16 + r] = bv;
        out[(size_t)BQ * 16 + (size_t)q * 16 + r] = (float)bi;
      }
    }
  }
}

extern "C" void kernel_launch(void* const* d_in, const int* in_sizes, int n_in,
                              void* d_out, int out_size, void* d_ws, size_t ws_size,
                              hipStream_t stream) {
  const float* Q = (const float*)d_in[0];
  const float* M = (const float*)d_in[1];
  int N = in_sizes[1] / DDIM;
  float* out = (float*)d_out;

  int nb = (N + 63) / 64;
  int Npitch = nb * 64;

  char* w = (char*)d_ws;
  size_t off = 0;
  auto alloc = [&](size_t bytes) {
    char* p = w + off;
    off = (off + bytes + 255) & ~(size_t)255;
    return p;
  };
  unsigned short* Qb = (unsigned short*)alloc((size_t)BQ * DDIM * 2);
  float* qn = (float*)alloc((size_t)BQ * 4);
  int* cand = (int*)alloc((size_t)BQ * NCAND * 4);
  unsigned short* sims = (unsigned short*)alloc((size_t)BQ * Npitch * 2);
  (void)ws_size;

  int Nc = (((N + CH - 1) / CH) + 7) & ~7;

  prep_q<<<BQ / 4, 256, 0, stream>>>(Q, Qb, qn);
  gemm_topk<<<nb, 256, 0, stream>>>(M, Qb, sims, N, Npitch);
  select_chunks<<<dim3(CH, BQ), 512, 0, stream>>>(sims, cand, N, Npitch, Nc);
  rescore<<<BQ, 512, 0, stream>>>(Q, M, qn, cand, out, N);
}